// Round 5
// baseline (220.277 us; speedup 1.0000x reference)
//
#include <hip/hip_runtime.h>
#include <hip/hip_bf16.h>

#define TSEQ 2048
#define CDIM 1024
#define NH 16
#define HS 64

typedef __attribute__((ext_vector_type(8))) short bf16x8;
typedef __attribute__((ext_vector_type(4))) float f32x4;
typedef __attribute__((ext_vector_type(16))) float f32x16;

__device__ inline void gload16(const void* g, void* l) {
    __builtin_amdgcn_global_load_lds((const __attribute__((address_space(1))) void*)g,
                                     (__attribute__((address_space(3))) void*)l, 16, 0, 0);
}

__device__ inline unsigned packbf(float a, float b) {
    union { __hip_bfloat162 h; unsigned u; } cv;
    cv.h = __float22bfloat162_rn(make_float2(a, b));
    return cv.u;
}

// ---------- elementwise f32 -> bf16 ----------
__global__ __launch_bounds__(256)
void conv_bf16(const float* __restrict__ in, __hip_bfloat16* __restrict__ out, int n) {
    int i = (blockIdx.x * 256 + threadIdx.x) * 4;
    if (i + 3 < n) {
        float4 v = *(const float4*)(in + i);
        union { ushort4 u; __hip_bfloat16 h[4]; } o;
        o.h[0] = __float2bfloat16(v.x);
        o.h[1] = __float2bfloat16(v.y);
        o.h[2] = __float2bfloat16(v.z);
        o.h[3] = __float2bfloat16(v.w);
        *(ushort4*)((unsigned short*)out + i) = o.u;
    }
}

// ---------- tiled transpose (+convert) : in [R][C] f32 -> out [C][R] bf16 ----------
__global__ __launch_bounds__(256)
void transpose_to_bf16(const float* __restrict__ in, __hip_bfloat16* __restrict__ out,
                       int R, int C) {
    __shared__ float t[32][33];
    const int tx = threadIdx.x & 31, ty = threadIdx.x >> 5;  // 32 x 8
    const int r0 = blockIdx.y * 32, c0 = blockIdx.x * 32;
    #pragma unroll
    for (int i = 0; i < 32; i += 8)
        t[ty + i][tx] = in[(size_t)(r0 + ty + i) * C + c0 + tx];
    __syncthreads();
    #pragma unroll
    for (int i = 0; i < 32; i += 8)
        out[(size_t)(c0 + ty + i) * R + r0 + tx] = __float2bfloat16(t[tx][ty + i]);
}

// ---------- fused QV GEMM: [H | V^T] = x @ [W1 | Wv] ----------
// X: [M][1024] bf16. W: [2048][1024] bf16 (rows 0..1023 = W1^T, 1024.. = Wv^T).
// cols < 1024: Hb[row][col] = relu(acc + bw1 + b1) bf16 row-major
// cols >=1024: Vt[col-1024][row] = acc + bv       bf16 TRANSPOSED [C][M]
__global__ __launch_bounds__(256, 2)
void gemm_qv(const __hip_bfloat16* __restrict__ X, const __hip_bfloat16* __restrict__ W,
             const float* __restrict__ bw1, const float* __restrict__ b1,
             const float* __restrict__ bv, __hip_bfloat16* __restrict__ Hb,
             __hip_bfloat16* __restrict__ Vt, int M)
{
    __shared__ __align__(16) __hip_bfloat16 As[128 * 32];
    __shared__ __align__(16) __hip_bfloat16 Bs[128 * 32];
    const int tid = threadIdx.x, wave = tid >> 6, lane = tid & 63;
    const int wr = wave >> 1, wc = wave & 1, l15 = lane & 15, l4 = lane >> 4;
    const int m0 = blockIdx.y * 128, n0 = blockIdx.x * 128;
    const int K = CDIM;
    const int srow = wave * 32 + (lane >> 2), scol = (lane & 3) * 8;
    const __hip_bfloat16* xg = X + (size_t)(m0 + srow) * K + scol;
    const __hip_bfloat16* wg = W + (size_t)(n0 + srow) * K + scol;
    __hip_bfloat16* la = &As[wave * 32 * 32];
    __hip_bfloat16* lb = &Bs[wave * 32 * 32];

    f32x4 acc[4][4] = {};
    for (int k0 = 0; k0 < K; k0 += 32) {
        __syncthreads();
        gload16(xg + k0, la);
        gload16(xg + k0 + (size_t)16 * K, la + 16 * 32);
        gload16(wg + k0, lb);
        gload16(wg + k0 + (size_t)16 * K, lb + 16 * 32);
        __syncthreads();
        bf16x8 af[4], bfr[4];
        #pragma unroll
        for (int f = 0; f < 4; f++) af[f]  = *(const bf16x8*)&As[(wr * 64 + f * 16 + l15) * 32 + l4 * 8];
        #pragma unroll
        for (int f = 0; f < 4; f++) bfr[f] = *(const bf16x8*)&Bs[(wc * 64 + f * 16 + l15) * 32 + l4 * 8];
        #pragma unroll
        for (int fr = 0; fr < 4; fr++)
            #pragma unroll
            for (int fc = 0; fc < 4; fc++)
                acc[fr][fc] = __builtin_amdgcn_mfma_f32_16x16x32_bf16(af[fr], bfr[fc], acc[fr][fc], 0, 0, 0);
    }

    const bool isH = (n0 < CDIM);
    #pragma unroll
    for (int fc = 0; fc < 4; fc++) {
        const int col = n0 + wc * 64 + fc * 16 + l15;
        if (isH) {
            const float bias = bw1[col] + b1[col & (HS - 1)];
            #pragma unroll
            for (int fr = 0; fr < 4; fr++)
                #pragma unroll
                for (int r = 0; r < 4; r++) {
                    const int row = m0 + wr * 64 + fr * 16 + l4 * 4 + r;
                    Hb[(size_t)row * CDIM + col] = __float2bfloat16(fmaxf(acc[fr][fc][r] + bias, 0.f));
                }
        } else {
            const int c2 = col - CDIM;
            const float bias = bv[c2];
            #pragma unroll
            for (int fr = 0; fr < 4; fr++) {
                const int rowb = m0 + wr * 64 + fr * 16 + l4 * 4;
                union { ushort4 u; __hip_bfloat16 h[4]; } o;
                #pragma unroll
                for (int r = 0; r < 4; r++) o.h[r] = __float2bfloat16(acc[fr][fc][r] + bias);
                *(ushort4*)(Vt + (size_t)c2 * M + rowb) = o.u;
            }
        }
    }
}

// ---------- projection GEMM: out = Y @ Wp + bp (f32 out) ----------
__global__ __launch_bounds__(256, 2)
void gemm_proj(const __hip_bfloat16* __restrict__ X, const __hip_bfloat16* __restrict__ Wt,
               const float* __restrict__ bN, float* __restrict__ Out, int M)
{
    __shared__ __align__(16) __hip_bfloat16 As[128 * 32];
    __shared__ __align__(16) __hip_bfloat16 Bs[128 * 32];
    const int tid = threadIdx.x, wave = tid >> 6, lane = tid & 63;
    const int wr = wave >> 1, wc = wave & 1, l15 = lane & 15, l4 = lane >> 4;
    const int m0 = blockIdx.y * 128, n0 = blockIdx.x * 128;
    const int K = CDIM;
    const int srow = wave * 32 + (lane >> 2), scol = (lane & 3) * 8;
    const __hip_bfloat16* xg = X + (size_t)(m0 + srow) * K + scol;
    const __hip_bfloat16* wg = Wt + (size_t)(n0 + srow) * K + scol;
    __hip_bfloat16* la = &As[wave * 32 * 32];
    __hip_bfloat16* lb = &Bs[wave * 32 * 32];

    f32x4 acc[4][4] = {};
    for (int k0 = 0; k0 < K; k0 += 32) {
        __syncthreads();
        gload16(xg + k0, la);
        gload16(xg + k0 + (size_t)16 * K, la + 16 * 32);
        gload16(wg + k0, lb);
        gload16(wg + k0 + (size_t)16 * K, lb + 16 * 32);
        __syncthreads();
        bf16x8 af[4], bfr[4];
        #pragma unroll
        for (int f = 0; f < 4; f++) af[f]  = *(const bf16x8*)&As[(wr * 64 + f * 16 + l15) * 32 + l4 * 8];
        #pragma unroll
        for (int f = 0; f < 4; f++) bfr[f] = *(const bf16x8*)&Bs[(wc * 64 + f * 16 + l15) * 32 + l4 * 8];
        #pragma unroll
        for (int fr = 0; fr < 4; fr++)
            #pragma unroll
            for (int fc = 0; fc < 4; fc++)
                acc[fr][fc] = __builtin_amdgcn_mfma_f32_16x16x32_bf16(af[fr], bfr[fc], acc[fr][fc], 0, 0, 0);
    }

    #pragma unroll
    for (int fc = 0; fc < 4; fc++) {
        const int col = n0 + wc * 64 + fc * 16 + l15;
        const float bias = bN[col];
        #pragma unroll
        for (int fr = 0; fr < 4; fr++)
            #pragma unroll
            for (int r = 0; r < 4; r++) {
                const int row = m0 + wr * 64 + fr * 16 + l4 * 4 + r;
                Out[(size_t)row * CDIM + col] = acc[fr][fc][r] + bias;
            }
    }
}

// ---------- fused synthesizer attention, 32x32x16 MFMA, in-register P ----------
// H: [B*T][C] bf16; w2t: [T][HS] bf16; Vt: [C][B*T] bf16; Y: [B*T][C] bf16.
// Block = 128 threads (2 waves), q-tile 128 (wave owns 64 q). K-tile 64.
// S^T = mfma(A=K, B=H) -> lane-local P rows -> pack+shfl to PV A-frags (no P LDS).
__global__ __launch_bounds__(128, 2)
void attn_mfma2(const __hip_bfloat16* __restrict__ H, const __hip_bfloat16* __restrict__ w2t,
                const __hip_bfloat16* __restrict__ Vt, const float* __restrict__ b2,
                __hip_bfloat16* __restrict__ Y, int M)
{
    __shared__ __align__(16) __hip_bfloat16 Ks[64 * 64];  // [t][hs], XOR-swizzled
    __shared__ __align__(16) __hip_bfloat16 Vs[64 * 64];  // [d][t],  XOR-swizzled
    __shared__ float Es[64];
    __shared__ float Ls[2 * 64];

    const int tid = threadIdx.x;
    const int w = tid >> 6, lane = tid & 63;
    const int l31 = lane & 31, hi = lane >> 5;
    const int h = blockIdx.y, b = blockIdx.z;
    const int u = (blockIdx.x + blockIdx.y) & 15;
    const int qb = b ? (15 - u) : u;        // causal load-balance pairing
    const int q0 = qb * 128;
    const int swz = l31 & 7;

    // H fragments (B-operand: col=lane&31=q, k=hi*8+j), held in registers
    bf16x8 hf[2][4];
    #pragma unroll
    for (int qf = 0; qf < 2; qf++) {
        const size_t row = (size_t)(b * TSEQ + q0 + w * 64 + qf * 32 + l31);
        #pragma unroll
        for (int kk = 0; kk < 4; kk++)
            hf[qf][kk] = *(const bf16x8*)(H + row * CDIM + h * HS + kk * 16 + hi * 8);
    }

    f32x16 yacc[2][2] = {};
    float lsum[2] = {0.f, 0.f};
    const int ntile = 2 * qb + 2;
    const int qmaxw = q0 + w * 64 + 63;

    for (int kt = 0; kt < ntile; kt++) {
        const int k0 = kt * 64;
        __syncthreads();
        #pragma unroll
        for (int uu = 0; uu < 4; uu++) {
            const int ui = tid + uu * 128;
            const int r = ui >> 3, c = ui & 7;
            const int cs = c ^ (r & 7);
            *(float4*)((char*)Ks + r * 128 + cs * 16) =
                *(const float4*)(w2t + (size_t)(k0 + r) * HS + c * 8);
            *(float4*)((char*)Vs + r * 128 + cs * 16) =
                *(const float4*)(Vt + (size_t)(h * HS + r) * M + b * TSEQ + k0 + c * 8);
        }
        if (tid < 64) Es[tid] = __expf(b2[k0 + tid]);
        __syncthreads();
        if (k0 > qmaxw) continue;   // fully-masked for this wave (barriers stay matched)

        bf16x8 pa[2][4];
        #pragma unroll
        for (int tf = 0; tf < 2; tf++) {
            // QK^T (swapped): st[qf] = K_frag x H_frag, D rows = t, cols = q
            f32x16 st[2] = {};
            #pragma unroll
            for (int kk = 0; kk < 4; kk++) {
                const int cs = (kk * 2 + hi) ^ swz;
                bf16x8 kf = *(const bf16x8*)((const char*)Ks + (tf * 32 + l31) * 128 + cs * 16);
                st[0] = __builtin_amdgcn_mfma_f32_32x32x16_bf16(kf, hf[0][kk], st[0], 0, 0, 0);
                st[1] = __builtin_amdgcn_mfma_f32_32x32x16_bf16(kf, hf[1][kk], st[1], 0, 0, 0);
            }
            float4 eb[4];
            #pragma unroll
            for (int g = 0; g < 4; g++) eb[g] = *(const float4*)&Es[tf * 32 + g * 8 + hi * 4];
            #pragma unroll
            for (int qf = 0; qf < 2; qf++) {
                const int qg = q0 + w * 64 + qf * 32 + l31;
                float p[16];
                #pragma unroll
                for (int r = 0; r < 16; r++) {
                    const int tg = k0 + tf * 32 + (r & 3) + 8 * (r >> 2) + 4 * hi;
                    float e = 0.f;
                    if (tg <= qg)
                        e = __expf(st[qf][r] + ((const float*)&eb[r >> 2])[r & 3]);
                    p[r] = e;
                    lsum[qf] += e;
                }
                // pack P into PV A-fragments (lane=q, k=t) via cvtpk + shfl_xor(32)
                #pragma unroll
                for (int m = 0; m < 2; m++) {
                    unsigned xA = packbf(p[8 * m + 0], p[8 * m + 1]);
                    unsigned xB = packbf(p[8 * m + 2], p[8 * m + 3]);
                    unsigned xC = packbf(p[8 * m + 4], p[8 * m + 5]);
                    unsigned xD = packbf(p[8 * m + 6], p[8 * m + 7]);
                    unsigned yA = (unsigned)__shfl_xor((int)xA, 32);
                    unsigned yB = (unsigned)__shfl_xor((int)xB, 32);
                    unsigned yC = (unsigned)__shfl_xor((int)xC, 32);
                    unsigned yD = (unsigned)__shfl_xor((int)xD, 32);
                    union { unsigned d[4]; bf16x8 v; } pk;
                    pk.d[0] = hi ? yC : xA;
                    pk.d[1] = hi ? yD : xB;
                    pk.d[2] = hi ? xC : yA;
                    pk.d[3] = hi ? xD : yB;
                    pa[qf][tf * 2 + m] = pk.v;
                }
            }
        }
        // PV: Y += P @ V_tile
        #pragma unroll
        for (int ks = 0; ks < 4; ks++) {
            const int cs = (ks * 2 + hi) ^ swz;
            #pragma unroll
            for (int df = 0; df < 2; df++) {
                bf16x8 vf = *(const bf16x8*)((const char*)Vs + (df * 32 + l31) * 128 + cs * 16);
                yacc[0][df] = __builtin_amdgcn_mfma_f32_32x32x16_bf16(pa[0][ks], vf, yacc[0][df], 0, 0, 0);
                yacc[1][df] = __builtin_amdgcn_mfma_f32_32x32x16_bf16(pa[1][ks], vf, yacc[1][df], 0, 0, 0);
            }
        }
    }

    // row-sum finalize: both halves hold partials; combine, publish via LDS
    lsum[0] += __shfl_xor(lsum[0], 32);
    lsum[1] += __shfl_xor(lsum[1], 32);
    if (hi == 0) { Ls[w * 64 + l31] = lsum[0]; Ls[w * 64 + 32 + l31] = lsum[1]; }
    __syncthreads();

    #pragma unroll
    for (int qf = 0; qf < 2; qf++)
        #pragma unroll
        for (int g = 0; g < 4; g++) {
            float4 lv = *(const float4*)&Ls[w * 64 + qf * 32 + g * 8 + hi * 4];
            #pragma unroll
            for (int df = 0; df < 2; df++)
                #pragma unroll
                for (int rr = 0; rr < 4; rr++) {
                    const float v = yacc[qf][df][g * 4 + rr] / ((const float*)&lv)[rr];
                    const size_t row = (size_t)(b * TSEQ + q0 + w * 64 + qf * 32 + 8 * g + 4 * hi + rr);
                    Y[row * CDIM + h * HS + df * 32 + l31] = __float2bfloat16(v);
                }
        }
}

extern "C" void kernel_launch(void* const* d_in, const int* in_sizes, int n_in,
                              void* d_out, int out_size, void* d_ws, size_t ws_size,
                              hipStream_t stream) {
    const float* x   = (const float*)d_in[0];
    const float* W1  = (const float*)d_in[1];
    const float* bw1 = (const float*)d_in[2];
    const float* b1  = (const float*)d_in[3];
    const float* w2  = (const float*)d_in[4];
    const float* b2  = (const float*)d_in[5];
    const float* Wv  = (const float*)d_in[6];
    const float* bv  = (const float*)d_in[7];
    const float* Wp  = (const float*)d_in[8];
    const float* bp  = (const float*)d_in[9];
    float* out = (float*)d_out;

    const int B = in_sizes[0] / (TSEQ * CDIM);   // 2
    const int M = B * TSEQ;                      // 4096
    const size_t MC = (size_t)M * CDIM;          // 4M
    const size_t WC = (size_t)CDIM * CDIM;       // 1M

    __hip_bfloat16* xb  = (__hip_bfloat16*)d_ws;
    __hip_bfloat16* Wqv = xb  + MC;              // [2048][1024]: W1t then Wvt
    __hip_bfloat16* Wpt = Wqv + 2 * WC;
    __hip_bfloat16* w2t = Wpt + WC;              // [T][HS]
    __hip_bfloat16* Hb  = w2t + (size_t)TSEQ * HS;
    __hip_bfloat16* Vtb = Hb  + MC;              // [C][M]
    __hip_bfloat16* Yb  = Vtb + MC;

    dim3 blk(256);
    conv_bf16<<<dim3((unsigned)(MC / 1024)), blk, 0, stream>>>(x, xb, (int)MC);
    transpose_to_bf16<<<dim3(32, 32), blk, 0, stream>>>(W1, Wqv, CDIM, CDIM);
    transpose_to_bf16<<<dim3(32, 32), blk, 0, stream>>>(Wv, Wqv + WC, CDIM, CDIM);
    transpose_to_bf16<<<dim3(32, 32), blk, 0, stream>>>(Wp, Wpt, CDIM, CDIM);
    transpose_to_bf16<<<dim3(TSEQ / 32, HS / 32), blk, 0, stream>>>(w2, w2t, HS, TSEQ);

    gemm_qv<<<dim3(16, M / 128), blk, 0, stream>>>(xb, Wqv, bw1, b1, bv, Hb, Vtb, M);

    attn_mfma2<<<dim3(16, NH, B), dim3(128), 0, stream>>>(Hb, w2t, Vtb, b2, Yb, M);

    gemm_proj<<<dim3(8, M / 128), blk, 0, stream>>>(Yb, Wpt, bp, out, M);
}

// Round 6
// 163.357 us; speedup vs baseline: 1.3484x; 1.3484x over previous
//
#include <hip/hip_runtime.h>
#include <hip/hip_bf16.h>

#define TSEQ 2048
#define CDIM 1024
#define NH 16
#define HS 64

typedef __attribute__((ext_vector_type(8))) short bf16x8;
typedef __attribute__((ext_vector_type(4))) float f32x4;
typedef __attribute__((ext_vector_type(16))) float f32x16;

__device__ inline void gload16(const void* g, void* l) {
    __builtin_amdgcn_global_load_lds((const __attribute__((address_space(1))) void*)g,
                                     (__attribute__((address_space(3))) void*)l, 16, 0, 0);
}

__device__ inline unsigned packbf(float a, float b) {
    union { __hip_bfloat162 h; unsigned u; } cv;
    cv.h = __float22bfloat162_rn(make_float2(a, b));
    return cv.u;
}

// ---------- elementwise f32 -> bf16 ----------
__global__ __launch_bounds__(256)
void conv_bf16(const float* __restrict__ in, __hip_bfloat16* __restrict__ out, int n) {
    int i = (blockIdx.x * 256 + threadIdx.x) * 4;
    if (i + 3 < n) {
        float4 v = *(const float4*)(in + i);
        union { ushort4 u; __hip_bfloat16 h[4]; } o;
        o.h[0] = __float2bfloat16(v.x);
        o.h[1] = __float2bfloat16(v.y);
        o.h[2] = __float2bfloat16(v.z);
        o.h[3] = __float2bfloat16(v.w);
        *(ushort4*)((unsigned short*)out + i) = o.u;
    }
}

// ---------- tiled transpose (+convert) : in [R][C] f32 -> out [C][R] bf16 ----------
__global__ __launch_bounds__(256)
void transpose_to_bf16(const float* __restrict__ in, __hip_bfloat16* __restrict__ out,
                       int R, int C) {
    __shared__ float t[32][33];
    const int tx = threadIdx.x & 31, ty = threadIdx.x >> 5;  // 32 x 8
    const int r0 = blockIdx.y * 32, c0 = blockIdx.x * 32;
    #pragma unroll
    for (int i = 0; i < 32; i += 8)
        t[ty + i][tx] = in[(size_t)(r0 + ty + i) * C + c0 + tx];
    __syncthreads();
    #pragma unroll
    for (int i = 0; i < 32; i += 8)
        out[(size_t)(c0 + ty + i) * R + r0 + tx] = __float2bfloat16(t[tx][ty + i]);
}

// ---------- fused QV GEMM: [H | V^T] = x @ [W1 | Wv] ----------
__global__ __launch_bounds__(256, 2)
void gemm_qv(const __hip_bfloat16* __restrict__ X, const __hip_bfloat16* __restrict__ W,
             const float* __restrict__ bw1, const float* __restrict__ b1,
             const float* __restrict__ bv, __hip_bfloat16* __restrict__ Hb,
             __hip_bfloat16* __restrict__ Vt, int M)
{
    __shared__ __align__(16) __hip_bfloat16 As[128 * 32];
    __shared__ __align__(16) __hip_bfloat16 Bs[128 * 32];
    const int tid = threadIdx.x, wave = tid >> 6, lane = tid & 63;
    const int wr = wave >> 1, wc = wave & 1, l15 = lane & 15, l4 = lane >> 4;
    const int m0 = blockIdx.y * 128, n0 = blockIdx.x * 128;
    const int K = CDIM;
    const int srow = wave * 32 + (lane >> 2), scol = (lane & 3) * 8;
    const __hip_bfloat16* xg = X + (size_t)(m0 + srow) * K + scol;
    const __hip_bfloat16* wg = W + (size_t)(n0 + srow) * K + scol;
    __hip_bfloat16* la = &As[wave * 32 * 32];
    __hip_bfloat16* lb = &Bs[wave * 32 * 32];

    f32x4 acc[4][4] = {};
    for (int k0 = 0; k0 < K; k0 += 32) {
        __syncthreads();
        gload16(xg + k0, la);
        gload16(xg + k0 + (size_t)16 * K, la + 16 * 32);
        gload16(wg + k0, lb);
        gload16(wg + k0 + (size_t)16 * K, lb + 16 * 32);
        __syncthreads();
        bf16x8 af[4], bfr[4];
        #pragma unroll
        for (int f = 0; f < 4; f++) af[f]  = *(const bf16x8*)&As[(wr * 64 + f * 16 + l15) * 32 + l4 * 8];
        #pragma unroll
        for (int f = 0; f < 4; f++) bfr[f] = *(const bf16x8*)&Bs[(wc * 64 + f * 16 + l15) * 32 + l4 * 8];
        #pragma unroll
        for (int fr = 0; fr < 4; fr++)
            #pragma unroll
            for (int fc = 0; fc < 4; fc++)
                acc[fr][fc] = __builtin_amdgcn_mfma_f32_16x16x32_bf16(af[fr], bfr[fc], acc[fr][fc], 0, 0, 0);
    }

    const bool isH = (n0 < CDIM);
    #pragma unroll
    for (int fc = 0; fc < 4; fc++) {
        const int col = n0 + wc * 64 + fc * 16 + l15;
        if (isH) {
            const float bias = bw1[col] + b1[col & (HS - 1)];
            #pragma unroll
            for (int fr = 0; fr < 4; fr++)
                #pragma unroll
                for (int r = 0; r < 4; r++) {
                    const int row = m0 + wr * 64 + fr * 16 + l4 * 4 + r;
                    Hb[(size_t)row * CDIM + col] = __float2bfloat16(fmaxf(acc[fr][fc][r] + bias, 0.f));
                }
        } else {
            const int c2 = col - CDIM;
            const float bias = bv[c2];
            #pragma unroll
            for (int fr = 0; fr < 4; fr++) {
                const int rowb = m0 + wr * 64 + fr * 16 + l4 * 4;
                union { ushort4 u; __hip_bfloat16 h[4]; } o;
                #pragma unroll
                for (int r = 0; r < 4; r++) o.h[r] = __float2bfloat16(acc[fr][fc][r] + bias);
                *(ushort4*)(Vt + (size_t)c2 * M + rowb) = o.u;
            }
        }
    }
}

// ---------- projection GEMM: out = Y @ Wp + bp (f32 out) ----------
__global__ __launch_bounds__(256, 2)
void gemm_proj(const __hip_bfloat16* __restrict__ X, const __hip_bfloat16* __restrict__ Wt,
               const float* __restrict__ bN, float* __restrict__ Out, int M)
{
    __shared__ __align__(16) __hip_bfloat16 As[128 * 32];
    __shared__ __align__(16) __hip_bfloat16 Bs[128 * 32];
    const int tid = threadIdx.x, wave = tid >> 6, lane = tid & 63;
    const int wr = wave >> 1, wc = wave & 1, l15 = lane & 15, l4 = lane >> 4;
    const int m0 = blockIdx.y * 128, n0 = blockIdx.x * 128;
    const int K = CDIM;
    const int srow = wave * 32 + (lane >> 2), scol = (lane & 3) * 8;
    const __hip_bfloat16* xg = X + (size_t)(m0 + srow) * K + scol;
    const __hip_bfloat16* wg = Wt + (size_t)(n0 + srow) * K + scol;
    __hip_bfloat16* la = &As[wave * 32 * 32];
    __hip_bfloat16* lb = &Bs[wave * 32 * 32];

    f32x4 acc[4][4] = {};
    for (int k0 = 0; k0 < K; k0 += 32) {
        __syncthreads();
        gload16(xg + k0, la);
        gload16(xg + k0 + (size_t)16 * K, la + 16 * 32);
        gload16(wg + k0, lb);
        gload16(wg + k0 + (size_t)16 * K, lb + 16 * 32);
        __syncthreads();
        bf16x8 af[4], bfr[4];
        #pragma unroll
        for (int f = 0; f < 4; f++) af[f]  = *(const bf16x8*)&As[(wr * 64 + f * 16 + l15) * 32 + l4 * 8];
        #pragma unroll
        for (int f = 0; f < 4; f++) bfr[f] = *(const bf16x8*)&Bs[(wc * 64 + f * 16 + l15) * 32 + l4 * 8];
        #pragma unroll
        for (int fr = 0; fr < 4; fr++)
            #pragma unroll
            for (int fc = 0; fc < 4; fc++)
                acc[fr][fc] = __builtin_amdgcn_mfma_f32_16x16x32_bf16(af[fr], bfr[fc], acc[fr][fc], 0, 0, 0);
    }

    #pragma unroll
    for (int fc = 0; fc < 4; fc++) {
        const int col = n0 + wc * 64 + fc * 16 + l15;
        const float bias = bN[col];
        #pragma unroll
        for (int fr = 0; fr < 4; fr++)
            #pragma unroll
            for (int r = 0; r < 4; r++) {
                const int row = m0 + wr * 64 + fr * 16 + l4 * 4 + r;
                Out[(size_t)row * CDIM + col] = acc[fr][fc][r] + bias;
            }
    }
}

// ---------- fused synthesizer attention, 32x32x16 MFMA, in-register P ----------
// 4 waves x 32 q-rows each; block q-tile 128; k-tile 64. Swapped QK (S^T) ->
// lane-local P rows -> pack + shfl_xor(32) into PV A-frags. No P LDS traffic.
__global__ __launch_bounds__(256, 2)
void attn_mfma3(const __hip_bfloat16* __restrict__ H, const __hip_bfloat16* __restrict__ w2t,
                const __hip_bfloat16* __restrict__ Vt, const float* __restrict__ b2,
                __hip_bfloat16* __restrict__ Y, int M)
{
    __shared__ __align__(16) __hip_bfloat16 Ks[64 * 64];  // [t][hs], XOR-swizzled
    __shared__ __align__(16) __hip_bfloat16 Vs[64 * 64];  // [d][t],  XOR-swizzled
    __shared__ float Es[64];
    __shared__ float Ls[4 * 32];

    const int tid = threadIdx.x;
    const int w = tid >> 6, lane = tid & 63;
    const int l31 = lane & 31, hi = lane >> 5;
    const int h = blockIdx.y, b = blockIdx.z;
    const int u = (blockIdx.x + blockIdx.y) & 15;
    const int qb = b ? (15 - u) : u;        // causal load-balance pairing
    const int q0 = qb * 128;
    const int qw = q0 + w * 32;             // this wave's first q row
    const int swz = l31 & 7;

    // H fragments (B-operand: col=lane&31=q, k=hi*8+j), in registers
    bf16x8 hf[4];
    {
        const size_t row = (size_t)(b * TSEQ + qw + l31);
        #pragma unroll
        for (int kk = 0; kk < 4; kk++)
            hf[kk] = *(const bf16x8*)(H + row * CDIM + h * HS + kk * 16 + hi * 8);
    }

    f32x16 yacc[2] = {};
    float lsum = 0.f;
    const int ntile = 2 * qb + 2;

    for (int kt = 0; kt < ntile; kt++) {
        const int k0 = kt * 64;
        __syncthreads();
        #pragma unroll
        for (int uu = 0; uu < 2; uu++) {
            const int ui = tid + uu * 256;
            const int r = ui >> 3, c = ui & 7;
            const int cs = c ^ (r & 7);
            *(float4*)((char*)Ks + r * 128 + cs * 16) =
                *(const float4*)(w2t + (size_t)(k0 + r) * HS + c * 8);
            *(float4*)((char*)Vs + r * 128 + cs * 16) =
                *(const float4*)(Vt + (size_t)(h * HS + r) * M + b * TSEQ + k0 + c * 8);
        }
        if (tid < 64) Es[tid] = __expf(b2[k0 + tid]);
        __syncthreads();
        if (k0 > qw + 31) continue;          // fully masked for this wave
        const bool nomask = (k0 + 63 <= qw); // tile entirely below diagonal

        bf16x8 pa[4];
        #pragma unroll
        for (int tf = 0; tf < 2; tf++) {
            f32x16 st = {};
            #pragma unroll
            for (int kk = 0; kk < 4; kk++) {
                const int cs = (kk * 2 + hi) ^ swz;
                bf16x8 kf = *(const bf16x8*)((const char*)Ks + (tf * 32 + l31) * 128 + cs * 16);
                st = __builtin_amdgcn_mfma_f32_32x32x16_bf16(kf, hf[kk], st, 0, 0, 0);
            }
            float4 eb[4];
            #pragma unroll
            for (int g = 0; g < 4; g++) eb[g] = *(const float4*)&Es[tf * 32 + g * 8 + hi * 4];
            const int qg = qw + l31;
            float p[16];
            #pragma unroll
            for (int r = 0; r < 16; r++) {
                // exp(s + b2) = exp(s) * exp(b2)  (correct for general b2)
                float e = __expf(st[r]) * ((const float*)&eb[r >> 2])[r & 3];
                if (!nomask) {
                    const int tg = k0 + tf * 32 + (r & 3) + 8 * (r >> 2) + 4 * hi;
                    if (tg > qg) e = 0.f;
                }
                p[r] = e;
                lsum += e;
            }
            #pragma unroll
            for (int m = 0; m < 2; m++) {
                unsigned xA = packbf(p[8 * m + 0], p[8 * m + 1]);
                unsigned xB = packbf(p[8 * m + 2], p[8 * m + 3]);
                unsigned xC = packbf(p[8 * m + 4], p[8 * m + 5]);
                unsigned xD = packbf(p[8 * m + 6], p[8 * m + 7]);
                unsigned yA = (unsigned)__shfl_xor((int)xA, 32);
                unsigned yB = (unsigned)__shfl_xor((int)xB, 32);
                unsigned yC = (unsigned)__shfl_xor((int)xC, 32);
                unsigned yD = (unsigned)__shfl_xor((int)xD, 32);
                union { unsigned d[4]; bf16x8 v; } pk;
                pk.d[0] = hi ? yC : xA;
                pk.d[1] = hi ? yD : xB;
                pk.d[2] = hi ? xC : yA;
                pk.d[3] = hi ? xD : yB;
                pa[tf * 2 + m] = pk.v;
            }
        }
        // PV: Y += P @ V_tile
        #pragma unroll
        for (int ks = 0; ks < 4; ks++) {
            const int cs = (ks * 2 + hi) ^ swz;
            #pragma unroll
            for (int df = 0; df < 2; df++) {
                bf16x8 vf = *(const bf16x8*)((const char*)Vs + (df * 32 + l31) * 128 + cs * 16);
                yacc[df] = __builtin_amdgcn_mfma_f32_32x32x16_bf16(pa[ks], vf, yacc[df], 0, 0, 0);
            }
        }
    }

    // combine the two k-halves (hi 0/1) of each q-row sum, publish per-wave
    lsum += __shfl_xor(lsum, 32);
    if (hi == 0) Ls[w * 32 + l31] = lsum;
    __syncthreads();

    #pragma unroll
    for (int g = 0; g < 4; g++) {
        float4 lv = *(const float4*)&Ls[w * 32 + g * 8 + hi * 4];
        #pragma unroll
        for (int df = 0; df < 2; df++)
            #pragma unroll
            for (int rr = 0; rr < 4; rr++) {
                const float v = yacc[df][g * 4 + rr] / ((const float*)&lv)[rr];
                const size_t row = (size_t)(b * TSEQ + qw + 8 * g + 4 * hi + rr);
                Y[row * CDIM + h * HS + df * 32 + l31] = __float2bfloat16(v);
            }
    }
}

extern "C" void kernel_launch(void* const* d_in, const int* in_sizes, int n_in,
                              void* d_out, int out_size, void* d_ws, size_t ws_size,
                              hipStream_t stream) {
    const float* x   = (const float*)d_in[0];
    const float* W1  = (const float*)d_in[1];
    const float* bw1 = (const float*)d_in[2];
    const float* b1  = (const float*)d_in[3];
    const float* w2  = (const float*)d_in[4];
    const float* b2  = (const float*)d_in[5];
    const float* Wv  = (const float*)d_in[6];
    const float* bv  = (const float*)d_in[7];
    const float* Wp  = (const float*)d_in[8];
    const float* bp  = (const float*)d_in[9];
    float* out = (float*)d_out;

    const int B = in_sizes[0] / (TSEQ * CDIM);   // 2
    const int M = B * TSEQ;                      // 4096
    const size_t MC = (size_t)M * CDIM;          // 4M
    const size_t WC = (size_t)CDIM * CDIM;       // 1M

    __hip_bfloat16* xb  = (__hip_bfloat16*)d_ws;
    __hip_bfloat16* Wqv = xb  + MC;              // [2048][1024]: W1t then Wvt
    __hip_bfloat16* Wpt = Wqv + 2 * WC;
    __hip_bfloat16* w2t = Wpt + WC;              // [T][HS]
    __hip_bfloat16* Hb  = w2t + (size_t)TSEQ * HS;
    __hip_bfloat16* Vtb = Hb  + MC;              // [C][M]
    __hip_bfloat16* Yb  = Vtb + MC;

    dim3 blk(256);
    conv_bf16<<<dim3((unsigned)(MC / 1024)), blk, 0, stream>>>(x, xb, (int)MC);
    transpose_to_bf16<<<dim3(32, 32), blk, 0, stream>>>(W1, Wqv, CDIM, CDIM);
    transpose_to_bf16<<<dim3(32, 32), blk, 0, stream>>>(Wv, Wqv + WC, CDIM, CDIM);
    transpose_to_bf16<<<dim3(32, 32), blk, 0, stream>>>(Wp, Wpt, CDIM, CDIM);
    transpose_to_bf16<<<dim3(TSEQ / 32, HS / 32), blk, 0, stream>>>(w2, w2t, HS, TSEQ);

    gemm_qv<<<dim3(16, M / 128), blk, 0, stream>>>(xb, Wqv, bw1, b1, bv, Hb, Vtb, M);

    attn_mfma3<<<dim3(16, NH, B), blk, 0, stream>>>(Hb, w2t, Vtb, b2, Yb, M);

    gemm_proj<<<dim3(8, M / 128), blk, 0, stream>>>(Yb, Wpt, bp, out, M);
}

// Round 8
// 140.897 us; speedup vs baseline: 1.5634x; 1.1594x over previous
//
#include <hip/hip_runtime.h>
#include <hip/hip_bf16.h>

#define TSEQ 2048
#define CDIM 1024
#define NH 16
#define HS 64

typedef __attribute__((ext_vector_type(8))) short bf16x8;
typedef __attribute__((ext_vector_type(4))) float f32x4;
typedef __attribute__((ext_vector_type(16))) float f32x16;

__device__ inline void gload16(const void* g, void* l) {
    __builtin_amdgcn_global_load_lds((const __attribute__((address_space(1))) void*)g,
                                     (__attribute__((address_space(3))) void*)l, 16, 0, 0);
}

__device__ inline unsigned packbf(float a, float b) {
    union { __hip_bfloat162 h; unsigned u; } cv;
    cv.h = __float22bfloat162_rn(make_float2(a, b));
    return cv.u;
}

// ---------- elementwise f32 -> bf16 ----------
__global__ __launch_bounds__(256)
void conv_bf16(const float* __restrict__ in, __hip_bfloat16* __restrict__ out, int n) {
    int i = (blockIdx.x * 256 + threadIdx.x) * 4;
    if (i + 3 < n) {
        float4 v = *(const float4*)(in + i);
        union { ushort4 u; __hip_bfloat16 h[4]; } o;
        o.h[0] = __float2bfloat16(v.x);
        o.h[1] = __float2bfloat16(v.y);
        o.h[2] = __float2bfloat16(v.z);
        o.h[3] = __float2bfloat16(v.w);
        *(ushort4*)((unsigned short*)out + i) = o.u;
    }
}

// ---------- exp(b2) precompute ----------
__global__ __launch_bounds__(256)
void exp_b2(const float* __restrict__ b2, float* __restrict__ eb2, int n) {
    int i = blockIdx.x * 256 + threadIdx.x;
    if (i < n) eb2[i] = __expf(b2[i]);
}

// ---------- tiled transpose (+convert) : in [R][C] f32 -> out [C][R] bf16 ----------
__global__ __launch_bounds__(256)
void transpose_to_bf16(const float* __restrict__ in, __hip_bfloat16* __restrict__ out,
                       int R, int C) {
    __shared__ float t[32][33];
    const int tx = threadIdx.x & 31, ty = threadIdx.x >> 5;  // 32 x 8
    const int r0 = blockIdx.y * 32, c0 = blockIdx.x * 32;
    #pragma unroll
    for (int i = 0; i < 32; i += 8)
        t[ty + i][tx] = in[(size_t)(r0 + ty + i) * C + c0 + tx];
    __syncthreads();
    #pragma unroll
    for (int i = 0; i < 32; i += 8)
        out[(size_t)(c0 + ty + i) * R + r0 + tx] = __float2bfloat16(t[tx][ty + i]);
}

// ---------- fused QV GEMM: [H | V^T] = x @ [W1 | Wv] ----------
// V^T written with sigma-permuted M index (swap bits 2<->3) so the attention
// kernel's PV B-operand lines up with the direct-packed P fragments (no shfl).
__global__ __launch_bounds__(256, 2)
void gemm_qv(const __hip_bfloat16* __restrict__ X, const __hip_bfloat16* __restrict__ W,
             const float* __restrict__ bw1, const float* __restrict__ b1,
             const float* __restrict__ bv, __hip_bfloat16* __restrict__ Hb,
             __hip_bfloat16* __restrict__ Vt, int M)
{
    __shared__ __align__(16) __hip_bfloat16 As[128 * 32];
    __shared__ __align__(16) __hip_bfloat16 Bs[128 * 32];
    const int tid = threadIdx.x, wave = tid >> 6, lane = tid & 63;
    const int wr = wave >> 1, wc = wave & 1, l15 = lane & 15, l4 = lane >> 4;
    const int m0 = blockIdx.y * 128, n0 = blockIdx.x * 128;
    const int K = CDIM;
    const int srow = wave * 32 + (lane >> 2), scol = (lane & 3) * 8;
    const __hip_bfloat16* xg = X + (size_t)(m0 + srow) * K + scol;
    const __hip_bfloat16* wg = W + (size_t)(n0 + srow) * K + scol;
    __hip_bfloat16* la = &As[wave * 32 * 32];
    __hip_bfloat16* lb = &Bs[wave * 32 * 32];

    f32x4 acc[4][4] = {};
    for (int k0 = 0; k0 < K; k0 += 32) {
        __syncthreads();
        gload16(xg + k0, la);
        gload16(xg + k0 + (size_t)16 * K, la + 16 * 32);
        gload16(wg + k0, lb);
        gload16(wg + k0 + (size_t)16 * K, lb + 16 * 32);
        __syncthreads();
        bf16x8 af[4], bfr[4];
        #pragma unroll
        for (int f = 0; f < 4; f++) af[f]  = *(const bf16x8*)&As[(wr * 64 + f * 16 + l15) * 32 + l4 * 8];
        #pragma unroll
        for (int f = 0; f < 4; f++) bfr[f] = *(const bf16x8*)&Bs[(wc * 64 + f * 16 + l15) * 32 + l4 * 8];
        #pragma unroll
        for (int fr = 0; fr < 4; fr++)
            #pragma unroll
            for (int fc = 0; fc < 4; fc++)
                acc[fr][fc] = __builtin_amdgcn_mfma_f32_16x16x32_bf16(af[fr], bfr[fc], acc[fr][fc], 0, 0, 0);
    }

    const bool isH = (n0 < CDIM);
    const int sl4 = ((l4 & 1) << 1) | (l4 >> 1);   // sigma: swap m-bits 2,3
    #pragma unroll
    for (int fc = 0; fc < 4; fc++) {
        const int col = n0 + wc * 64 + fc * 16 + l15;
        if (isH) {
            const float bias = bw1[col] + b1[col & (HS - 1)];
            #pragma unroll
            for (int fr = 0; fr < 4; fr++)
                #pragma unroll
                for (int r = 0; r < 4; r++) {
                    const int row = m0 + wr * 64 + fr * 16 + l4 * 4 + r;
                    Hb[(size_t)row * CDIM + col] = __float2bfloat16(fmaxf(acc[fr][fc][r] + bias, 0.f));
                }
        } else {
            const int c2 = col - CDIM;
            const float bias = bv[c2];
            #pragma unroll
            for (int fr = 0; fr < 4; fr++) {
                const int rowb = m0 + wr * 64 + fr * 16 + sl4 * 4;
                union { ushort4 u; __hip_bfloat16 h[4]; } o;
                #pragma unroll
                for (int r = 0; r < 4; r++) o.h[r] = __float2bfloat16(acc[fr][fc][r] + bias);
                *(ushort4*)(Vt + (size_t)c2 * M + rowb) = o.u;
            }
        }
    }
}

// ---------- projection GEMM: out = Y @ Wp + bp (f32 out) ----------
__global__ __launch_bounds__(256, 2)
void gemm_proj(const __hip_bfloat16* __restrict__ X, const __hip_bfloat16* __restrict__ Wt,
               const float* __restrict__ bN, float* __restrict__ Out, int M)
{
    __shared__ __align__(16) __hip_bfloat16 As[128 * 32];
    __shared__ __align__(16) __hip_bfloat16 Bs[128 * 32];
    const int tid = threadIdx.x, wave = tid >> 6, lane = tid & 63;
    const int wr = wave >> 1, wc = wave & 1, l15 = lane & 15, l4 = lane >> 4;
    const int m0 = blockIdx.y * 128, n0 = blockIdx.x * 128;
    const int K = CDIM;
    const int srow = wave * 32 + (lane >> 2), scol = (lane & 3) * 8;
    const __hip_bfloat16* xg = X + (size_t)(m0 + srow) * K + scol;
    const __hip_bfloat16* wg = Wt + (size_t)(n0 + srow) * K + scol;
    __hip_bfloat16* la = &As[wave * 32 * 32];
    __hip_bfloat16* lb = &Bs[wave * 32 * 32];

    f32x4 acc[4][4] = {};
    for (int k0 = 0; k0 < K; k0 += 32) {
        __syncthreads();
        gload16(xg + k0, la);
        gload16(xg + k0 + (size_t)16 * K, la + 16 * 32);
        gload16(wg + k0, lb);
        gload16(wg + k0 + (size_t)16 * K, lb + 16 * 32);
        __syncthreads();
        bf16x8 af[4], bfr[4];
        #pragma unroll
        for (int f = 0; f < 4; f++) af[f]  = *(const bf16x8*)&As[(wr * 64 + f * 16 + l15) * 32 + l4 * 8];
        #pragma unroll
        for (int f = 0; f < 4; f++) bfr[f] = *(const bf16x8*)&Bs[(wc * 64 + f * 16 + l15) * 32 + l4 * 8];
        #pragma unroll
        for (int fr = 0; fr < 4; fr++)
            #pragma unroll
            for (int fc = 0; fc < 4; fc++)
                acc[fr][fc] = __builtin_amdgcn_mfma_f32_16x16x32_bf16(af[fr], bfr[fc], acc[fr][fc], 0, 0, 0);
    }

    #pragma unroll
    for (int fc = 0; fc < 4; fc++) {
        const int col = n0 + wc * 64 + fc * 16 + l15;
        const float bias = bN[col];
        #pragma unroll
        for (int fr = 0; fr < 4; fr++)
            #pragma unroll
            for (int r = 0; r < 4; r++) {
                const int row = m0 + wr * 64 + fr * 16 + l4 * 4 + r;
                Out[(size_t)row * CDIM + col] = acc[fr][fc][r] + bias;
            }
    }
}

// ---------- fused synthesizer attention v4 ----------
// 4 waves x 32 q; double-buffered K/V via global_load_lds (source pre-swizzled,
// linear LDS); sigma-permuted V -> direct P pack (no shfl); exp(b2) from global.
__global__ __launch_bounds__(256, 2)
void attn_mfma4(const __hip_bfloat16* __restrict__ H, const __hip_bfloat16* __restrict__ w2t,
                const __hip_bfloat16* __restrict__ Vt, const float* __restrict__ eb2,
                __hip_bfloat16* __restrict__ Y, int M)
{
    __shared__ __align__(16) __hip_bfloat16 Ks[2][64 * 64];  // [t][hs] XOR-swizzled
    __shared__ __align__(16) __hip_bfloat16 Vs[2][64 * 64];  // [d][t(sigma)] XOR-swizzled
    __shared__ float Ls[4 * 32];

    const int tid = threadIdx.x;
    const int w = tid >> 6, lane = tid & 63;
    const int l31 = lane & 31, hi = lane >> 5;
    const int h = blockIdx.y, b = blockIdx.z;
    const int u = (blockIdx.x + blockIdx.y) & 15;
    const int qb = b ? (15 - u) : u;        // causal load-balance pairing
    const int q0 = qb * 128;
    const int qw = q0 + w * 32;             // this wave's first q row
    const int swz = l31 & 7;

    // per-lane staging geometry: wave w stages K/V rows w*16 .. w*16+15
    const int srr = lane >> 3, spc = lane & 7;
    const int sr0 = w * 16 + srr, sr1 = w * 16 + 8 + srr;
    const int sc0 = (spc ^ (sr0 & 7)) * 8;   // source col pre-XOR (involution)
    const int sc1 = (spc ^ (sr1 & 7)) * 8;
    const __hip_bfloat16* kg0 = w2t + (size_t)sr0 * HS + sc0;
    const __hip_bfloat16* kg1 = w2t + (size_t)sr1 * HS + sc1;
    const __hip_bfloat16* vg0 = Vt + (size_t)(h * HS + sr0) * M + b * TSEQ + sc0;
    const __hip_bfloat16* vg1 = Vt + (size_t)(h * HS + sr1) * M + b * TSEQ + sc1;

    // H fragments (B-operand: col=lane&31=q, k=hi*8+j), in registers
    bf16x8 hf[4];
    {
        const size_t row = (size_t)(b * TSEQ + qw + l31);
        #pragma unroll
        for (int kk = 0; kk < 4; kk++)
            hf[kk] = *(const bf16x8*)(H + row * CDIM + h * HS + kk * 16 + hi * 8);
    }

    f32x16 yacc[2] = {};
    float lsum = 0.f;
    const int ntile = 2 * qb + 2;

    // prologue: stage tile 0 into buffer 0
    gload16(kg0, &Ks[0][(w * 16) * 64]);
    gload16(kg1, &Ks[0][(w * 16 + 8) * 64]);
    gload16(vg0, &Vs[0][(w * 16) * 64]);
    gload16(vg1, &Vs[0][(w * 16 + 8) * 64]);
    __syncthreads();

    int cur = 0;
    for (int kt = 0; kt < ntile; kt++) {
        const int k0 = kt * 64;
        // stage next tile into the other buffer (overlaps with compute below)
        if (kt + 1 < ntile) {
            const int kn = (kt + 1) * 64;
            const int nb = cur ^ 1;
            gload16(kg0 + (size_t)kn * HS, &Ks[nb][(w * 16) * 64]);
            gload16(kg1 + (size_t)kn * HS, &Ks[nb][(w * 16 + 8) * 64]);
            gload16(vg0 + kn, &Vs[nb][(w * 16) * 64]);
            gload16(vg1 + kn, &Vs[nb][(w * 16 + 8) * 64]);
        }
        if (k0 <= qw + 31) {
            const bool nomask = (k0 + 63 <= qw);
            bf16x8 pa[4];
            #pragma unroll
            for (int tf = 0; tf < 2; tf++) {
                float4 eb[4];
                #pragma unroll
                for (int g = 0; g < 4; g++)
                    eb[g] = *(const float4*)(eb2 + k0 + tf * 32 + g * 8 + hi * 4);
                f32x16 st = {};
                #pragma unroll
                for (int kk = 0; kk < 4; kk++) {
                    const int cs = (kk * 2 + hi) ^ swz;
                    bf16x8 kf = *(const bf16x8*)((const char*)&Ks[cur][0] + (tf * 32 + l31) * 128 + cs * 16);
                    st = __builtin_amdgcn_mfma_f32_32x32x16_bf16(kf, hf[kk], st, 0, 0, 0);
                }
                const int qg = qw + l31;
                float p[16];
                #pragma unroll
                for (int r = 0; r < 16; r++) {
                    float e = __expf(st[r]) * ((const float*)&eb[r >> 2])[r & 3];
                    if (!nomask) {
                        const int tg = k0 + tf * 32 + (r & 3) + 8 * (r >> 2) + 4 * hi;
                        if (tg > qg) e = 0.f;
                    }
                    p[r] = e;
                    lsum += e;
                }
                // direct pack: A-slot j of chunk ks=2tf+m <- p[8m+j] (sigma'd V aligns)
                #pragma unroll
                for (int m = 0; m < 2; m++) {
                    union { unsigned d[4]; bf16x8 v; } pk;
                    #pragma unroll
                    for (int dw = 0; dw < 4; dw++)
                        pk.d[dw] = packbf(p[8 * m + 2 * dw], p[8 * m + 2 * dw + 1]);
                    pa[tf * 2 + m] = pk.v;
                }
            }
            // PV: Y += P @ V_tile
            #pragma unroll
            for (int ks = 0; ks < 4; ks++) {
                const int cs = (ks * 2 + hi) ^ swz;
                #pragma unroll
                for (int df = 0; df < 2; df++) {
                    bf16x8 vf = *(const bf16x8*)((const char*)&Vs[cur][0] + (df * 32 + l31) * 128 + cs * 16);
                    yacc[df] = __builtin_amdgcn_mfma_f32_32x32x16_bf16(pa[ks], vf, yacc[df], 0, 0, 0);
                }
            }
        }
        __syncthreads();   // drains next-tile staging loads; releases cur buffer
        cur ^= 1;
    }

    // combine the two k-halves (hi 0/1) of each q-row sum, publish per-wave
    lsum += __shfl_xor(lsum, 32);
    if (hi == 0) Ls[w * 32 + l31] = lsum;
    __syncthreads();

    #pragma unroll
    for (int g = 0; g < 4; g++) {
        float4 lv = *(const float4*)&Ls[w * 32 + g * 8 + hi * 4];
        #pragma unroll
        for (int df = 0; df < 2; df++)
            #pragma unroll
            for (int rr = 0; rr < 4; rr++) {
                const float v = yacc[df][g * 4 + rr] / ((const float*)&lv)[rr];
                const size_t row = (size_t)(b * TSEQ + qw + 8 * g + 4 * hi + rr);
                Y[row * CDIM + h * HS + df * 32 + l31] = __float2bfloat16(v);
            }
    }
}

extern "C" void kernel_launch(void* const* d_in, const int* in_sizes, int n_in,
                              void* d_out, int out_size, void* d_ws, size_t ws_size,
                              hipStream_t stream) {
    const float* x   = (const float*)d_in[0];
    const float* W1  = (const float*)d_in[1];
    const float* bw1 = (const float*)d_in[2];
    const float* b1  = (const float*)d_in[3];
    const float* w2  = (const float*)d_in[4];
    const float* b2  = (const float*)d_in[5];
    const float* Wv  = (const float*)d_in[6];
    const float* bv  = (const float*)d_in[7];
    const float* Wp  = (const float*)d_in[8];
    const float* bp  = (const float*)d_in[9];
    float* out = (float*)d_out;

    const int B = in_sizes[0] / (TSEQ * CDIM);   // 2
    const int M = B * TSEQ;                      // 4096
    const size_t MC = (size_t)M * CDIM;          // 4M
    const size_t WC = (size_t)CDIM * CDIM;       // 1M

    __hip_bfloat16* xb  = (__hip_bfloat16*)d_ws;
    __hip_bfloat16* Wqv = xb  + MC;              // [2048][1024]: W1t then Wvt
    __hip_bfloat16* Wpt = Wqv + 2 * WC;
    __hip_bfloat16* w2t = Wpt + WC;              // [T][HS]
    __hip_bfloat16* Hb  = w2t + (size_t)TSEQ * HS;
    __hip_bfloat16* Vtb = Hb  + MC;              // [C][M], sigma-permuted M
    __hip_bfloat16* Yb  = Vtb + MC;
    float*          eb2 = (float*)(Yb + MC);     // exp(b2), T floats

    dim3 blk(256);
    conv_bf16<<<dim3((unsigned)(MC / 1024)), blk, 0, stream>>>(x, xb, (int)MC);
    exp_b2<<<dim3(TSEQ / 256), blk, 0, stream>>>(b2, eb2, TSEQ);
    transpose_to_bf16<<<dim3(32, 32), blk, 0, stream>>>(W1, Wqv, CDIM, CDIM);
    transpose_to_bf16<<<dim3(32, 32), blk, 0, stream>>>(Wv, Wqv + WC, CDIM, CDIM);
    transpose_to_bf16<<<dim3(32, 32), blk, 0, stream>>>(Wp, Wpt, CDIM, CDIM);
    transpose_to_bf16<<<dim3(TSEQ / 32, HS / 32), blk, 0, stream>>>(w2, w2t, HS, TSEQ);

    gemm_qv<<<dim3(16, M / 128), blk, 0, stream>>>(xb, Wqv, bw1, b1, bv, Hb, Vtb, M);

    attn_mfma4<<<dim3(16, NH, B), blk, 0, stream>>>(Hb, w2t, Vtb, eb2, Yb, M);

    gemm_proj<<<dim3(8, M / 128), blk, 0, stream>>>(Yb, Wpt, bp, out, M);
}